// Round 5
// baseline (468.748 us; speedup 1.0000x reference)
//
#include <hip/hip_runtime.h>
#include <hip/hip_bf16.h>

#define M_TOK 16384   // B*S
#define DDIM  1024
#define NEXP  8
#define KP    (NEXP * DDIM)   // 8192 fused K

typedef __bf16 bf16x8 __attribute__((ext_vector_type(8)));
typedef __bf16 bf16x4 __attribute__((ext_vector_type(4)));
typedef float  floatx4 __attribute__((ext_vector_type(4)));

__device__ __forceinline__ void gload_lds16(const void* g, void* l) {
    __builtin_amdgcn_global_load_lds(
        (__attribute__((address_space(1))) void*)(void*)g,
        (__attribute__((address_space(3))) void*)l,
        16, 0, 0);
}

// ---------------------------------------------------------------------------
// Kernel 1 (merged prep): blocks [0,2048) convert W_edges fp32 -> Bp bf16
// [f][e*1024+k]; blocks [2048,6144) compute route softmax -> rw, h -> hbf.
// ---------------------------------------------------------------------------
#define CONV_BLOCKS  2048
#define ROUTE_BLOCKS 4096

__global__ __launch_bounds__(256) void prep_kernel(
    const float* __restrict__ h, const float* __restrict__ Wr,
    const float* __restrict__ br, const float* __restrict__ We,
    __bf16* __restrict__ hbf, float* __restrict__ rw, __bf16* __restrict__ Bp)
{
    __shared__ float Wrs[NEXP * DDIM];
    const int tid = threadIdx.x;

    if (blockIdx.x < CONV_BLOCKS) {
        size_t idx = ((size_t)blockIdx.x * 256 + tid) * 16;
        int e = (int)(idx >> 20);
        int f = (int)(idx >> 10) & 1023;
        int k = (int)idx & 1023;
        const float4* s4 = (const float4*)(We + idx);
        float a[16];
        #pragma unroll
        for (int i = 0; i < 4; ++i) {
            float4 v = s4[i];
            a[i*4+0] = v.x; a[i*4+1] = v.y; a[i*4+2] = v.z; a[i*4+3] = v.w;
        }
        bf16x8 o0, o1;
        #pragma unroll
        for (int i = 0; i < 8; ++i) { o0[i] = (__bf16)a[i]; o1[i] = (__bf16)a[8 + i]; }
        __bf16* d = Bp + (size_t)f * KP + (size_t)e * DDIM + k;
        *(bf16x8*)d       = o0;
        *(bf16x8*)(d + 8) = o1;
        return;
    }

    {
        const float4* s4 = (const float4*)Wr;
        float4* d4 = (float4*)Wrs;
        #pragma unroll
        for (int j = 0; j < 8; ++j) d4[j * 256 + tid] = s4[j * 256 + tid];
    }
    __syncthreads();

    const int wave = tid >> 6, lane = tid & 63;
    const int m = (blockIdx.x - CONV_BLOCKS) * 4 + wave;

    const float4* hrow4 = (const float4*)(h + (size_t)m * DDIM);
    float4 a[4];
    #pragma unroll
    for (int j = 0; j < 4; ++j) a[j] = hrow4[j * 64 + lane];

    #pragma unroll
    for (int j = 0; j < 4; ++j) {
        bf16x4 o;
        o[0] = (__bf16)a[j].x; o[1] = (__bf16)a[j].y;
        o[2] = (__bf16)a[j].z; o[3] = (__bf16)a[j].w;
        *(bf16x4*)(hbf + (size_t)m * DDIM + j * 256 + lane * 4) = o;
    }

    const float4* Wrs4 = (const float4*)Wrs;
    float p[NEXP];
    #pragma unroll
    for (int e = 0; e < NEXP; ++e) {
        float s = 0.f;
        #pragma unroll
        for (int j = 0; j < 4; ++j) {
            float4 wv = Wrs4[e * 256 + j * 64 + lane];
            s += a[j].x*wv.x + a[j].y*wv.y + a[j].z*wv.z + a[j].w*wv.w;
        }
        p[e] = s;
    }
    #pragma unroll
    for (int e = 0; e < NEXP; ++e) {
        #pragma unroll
        for (int off = 32; off > 0; off >>= 1)
            p[e] += __shfl_xor(p[e], off, 64);
    }
    if (lane == 0) {
        float l[NEXP], mx = -1e30f;
        #pragma unroll
        for (int e = 0; e < NEXP; ++e) { l[e] = p[e] + br[e]; mx = fmaxf(mx, l[e]); }
        float s = 0.f;
        #pragma unroll
        for (int e = 0; e < NEXP; ++e) { l[e] = expf(l[e] - mx); s += l[e]; }
        float inv = 1.f / s;
        float4 r0 = {l[0]*inv, l[1]*inv, l[2]*inv, l[3]*inv};
        float4 r1 = {l[4]*inv, l[5]*inv, l[6]*inv, l[7]*inv};
        *(float4*)(rw + (size_t)m * NEXP)     = r0;
        *(float4*)(rw + (size_t)m * NEXP + 4) = r1;
    }
}

// ---------------------------------------------------------------------------
// Kernel 2: fused MoE GEMM, 256x256 tile, BK=32, ring-4 LDS, distance-3
// prefetch, m201-faithful 4-phase-per-pair schedule, vmcnt(8) twice/pair.
//
// Pair (tiles a=2p, b=2p+1), slots sa=a&3, sb=b&3; stage tiles a+3 (ph1/ph2)
// and a+4 (ph3/ph4). Outstanding vmem oscillates 8..12, never drained <8.
//   top:  vmcnt(8) [drains a's 4 loads] ; BAR
//   ph1: reads bv_a[4]+av0_a[4]; gload A(a+3); BAR; lgkm(0); 16 MFMA lo(a); BAR
//   ph2: reads av1_a[4];         gload B(a+3); BAR; lgkm(0); 16 MFMA hi(a);
//        vmcnt(8) [drains b's]; BAR
//   ph3: reads bv_b[4]+av0_b[4]; gload A(a+4); BAR; lgkm(0); 16 MFMA lo(b); BAR
//   ph4: reads av1_b[4];         gload B(a+4); BAR; lgkm(0); 16 MFMA hi(b)
//        [post-barrier = next pair's top gate]
// WAR: stage(a+3) targets slot (a-1)&3, last read before this pair's top BAR;
//      stage(a+4) targets slot sa, last read before this pair's mid BAR.
// RAW: slot reads occur only after the gate that drains that tile's loads
//      (FIFO trace: top gate drains exactly tile a, mid gate exactly tile b).
//
// Expert rescale: 32 K-32 tiles per expert -> boundary at (a&31)==0, e=a>>5.
// (R4 bug: used the old K-128 arithmetic (a&7, a>>3) -> OOB rws reads.)
// Invariant: entering expert e, facc = (sum_{i<e} w_i*C_i)/w_e; boundary
// multiplies by w_{e-1}/w_e; epilogue multiplies by w_7.
// ---------------------------------------------------------------------------
__global__ __launch_bounds__(512, 2) void gemm_fused_kernel(
    const __bf16* __restrict__ hbf, const __bf16* __restrict__ Bp,
    const float* __restrict__ rw, const float* __restrict__ bias,
    float* __restrict__ outp)
{
    __shared__ __bf16 As[4][256 * 32];   // 4 x 16 KiB
    __shared__ __bf16 Bs[4][256 * 32];   // 4 x 16 KiB
    __shared__ float  rws[256 * 9];      // 9 KiB, padded stride 9

    const int tid  = threadIdx.x;
    const int wave = tid >> 6, lane = tid & 63;
    const int quad = lane >> 4, l16 = lane & 15;
    const int wm = wave >> 2, wn = wave & 3;          // 2 x 4 wave grid

    // Bijective XCD map: XCD = L&7 (dispatch round-robin). Two XCDs per
    // f-panel -> each XCD's 32 blocks share one 4 MiB B-slice (L2-resident).
    const int L = blockIdx.x;
    const int xcd = L & 7, slotid = L >> 3;
    const int f0 = (xcd >> 1) * 256;
    const int m0 = (((xcd & 1) << 5) + slotid) * 256;

    // stage routing weights for this block's 256 rows into padded LDS
    if (tid < 256) {
        const float4* s = (const float4*)(rw + ((size_t)m0 + tid) * NEXP);
        float4 x0 = s[0], x1 = s[1];
        float* d = &rws[tid * 9];
        d[0] = x0.x; d[1] = x0.y; d[2] = x0.z; d[3] = x0.w;
        d[4] = x1.x; d[5] = x1.y; d[6] = x1.z; d[7] = x1.w;
    }

    // LDS read offsets: row = 64B (4 groups of 16B); group swizzle g^=(row>>1)&3.
    const int arow = wm * 128 + l16;
    const int brow = wn * 64  + l16;
    const int aoff0 = (arow * 4 + (quad ^ ((arow >> 1) & 3))) * 16;
    const int boff0 = (brow * 4 + (quad ^ ((brow >> 1) & 3))) * 16;

    // staging: chunk c dst byte = c*8192 + tid*16; row = c*128 + (tid>>2);
    // pre-swizzled global source group (row+128 preserves (row>>1)&3)
    const int srow = tid >> 2;
    const int scol = ((tid & 3) ^ ((srow >> 1) & 3)) * 8;
    const size_t aBase = (size_t)(m0 + srow) * DDIM + scol;
    const size_t bBase = (size_t)(f0 + srow) * KP + scol;

    floatx4 facc[8][4];
    const floatx4 z4 = {0.f, 0.f, 0.f, 0.f};
    #pragma unroll
    for (int i = 0; i < 8; ++i)
        #pragma unroll
        for (int j = 0; j < 4; ++j) facc[i][j] = z4;

    __syncthreads();   // rws visible

    // prologue: stage tiles 0,1,2 (12 loads, grouped per tile, oldest first)
    #pragma unroll
    for (int t = 0; t < 3; ++t) {
        const __bf16* a0 = hbf + aBase + (t << 5);
        const __bf16* b0 = Bp  + bBase + (t << 5);
        char* ad = (char*)&As[t][0] + tid * 16;
        char* bd = (char*)&Bs[t][0] + tid * 16;
        gload_lds16(a0,            ad);
        gload_lds16(a0 + 131072,   ad + 8192);
        gload_lds16(b0,            bd);
        gload_lds16(b0 + 1048576,  bd + 8192);
    }

    #pragma unroll 1
    for (int p = 0; p < 128; ++p) {
        const int a = p << 1;
        if (a && (a & 31) == 0) {
            const int e = a >> 5;   // entering expert e (32 K-32 tiles/expert)
            #pragma unroll
            for (int mf = 0; mf < 8; ++mf) {
                #pragma unroll
                for (int r = 0; r < 4; ++r) {
                    int row = wm * 128 + mf * 16 + quad * 4 + r;
                    float wp = fmaxf(rws[row * 9 + e - 1], 1e-20f);
                    float wc = fmaxf(rws[row * 9 + e],     1e-20f);
                    float ratio = wp / wc;
                    #pragma unroll
                    for (int nf = 0; nf < 4; ++nf) facc[mf][nf][r] *= ratio;
                }
            }
        }
        const int sa = a & 3, sb = (a + 1) & 3;
        const int s3 = (a + 3) & 3, s4i = (a + 4) & 3;
        const __bf16* asrc3 = hbf + aBase + (size_t)(((a + 3) & 31) << 5);
        const __bf16* bsrc3 = Bp  + bBase + ((size_t)((a + 3) & 255) << 5);
        const __bf16* asrc4 = hbf + aBase + (size_t)(((a + 4) & 31) << 5);
        const __bf16* bsrc4 = Bp  + bBase + ((size_t)((a + 4) & 255) << 5);
        char* ad3 = (char*)&As[s3][0]  + tid * 16;
        char* bd3 = (char*)&Bs[s3][0]  + tid * 16;
        char* ad4 = (char*)&As[s4i][0] + tid * 16;
        char* bd4 = (char*)&Bs[s4i][0] + tid * 16;
        const char* Aa = (const char*)&As[sa][0];
        const char* Ba = (const char*)&Bs[sa][0];
        const char* Ab = (const char*)&As[sb][0];
        const char* Bb = (const char*)&Bs[sb][0];

        // ---- top gate: tile a's 4 loads are the oldest of 12 outstanding
        asm volatile("s_waitcnt vmcnt(8)" ::: "memory");
        asm volatile("s_barrier" ::: "memory");

        // ---- ph1: bv_a + av0_a; stage A(a+3); MFMA lo(a)
        bf16x8 bva[4], av0a[4], av1a[4];
        #pragma unroll
        for (int nf = 0; nf < 4; ++nf)
            bva[nf] = *(const bf16x8*)(Ba + boff0 + nf * 1024);
        #pragma unroll
        for (int mf = 0; mf < 4; ++mf)
            av0a[mf] = *(const bf16x8*)(Aa + aoff0 + mf * 1024);
        gload_lds16(asrc3,          ad3);
        gload_lds16(asrc3 + 131072, ad3 + 8192);

        asm volatile("s_barrier" ::: "memory");
        asm volatile("s_waitcnt lgkmcnt(0)" ::: "memory");
        __builtin_amdgcn_s_setprio(1);
        #pragma unroll
        for (int mf = 0; mf < 4; ++mf)
            #pragma unroll
            for (int nf = 0; nf < 4; ++nf)
                facc[mf][nf] = __builtin_amdgcn_mfma_f32_16x16x32_bf16(
                    av0a[mf], bva[nf], facc[mf][nf], 0, 0, 0);
        __builtin_amdgcn_s_setprio(0);
        asm volatile("s_barrier" ::: "memory");

        // ---- ph2: av1_a; stage B(a+3); MFMA hi(a); mid gate
        #pragma unroll
        for (int mf = 0; mf < 4; ++mf)
            av1a[mf] = *(const bf16x8*)(Aa + aoff0 + (4 + mf) * 1024);
        gload_lds16(bsrc3,           bd3);
        gload_lds16(bsrc3 + 1048576, bd3 + 8192);

        asm volatile("s_barrier" ::: "memory");
        asm volatile("s_waitcnt lgkmcnt(0)" ::: "memory");
        __builtin_amdgcn_s_setprio(1);
        #pragma unroll
        for (int mf = 0; mf < 4; ++mf)
            #pragma unroll
            for (int nf = 0; nf < 4; ++nf)
                facc[4 + mf][nf] = __builtin_amdgcn_mfma_f32_16x16x32_bf16(
                    av1a[mf], bva[nf], facc[4 + mf][nf], 0, 0, 0);
        __builtin_amdgcn_s_setprio(0);
        asm volatile("s_waitcnt vmcnt(8)" ::: "memory");   // drain tile b's loads
        asm volatile("s_barrier" ::: "memory");

        // ---- ph3: bv_b + av0_b; stage A(a+4); MFMA lo(b)
        bf16x8 bvb[4], av0b[4], av1b[4];
        #pragma unroll
        for (int nf = 0; nf < 4; ++nf)
            bvb[nf] = *(const bf16x8*)(Bb + boff0 + nf * 1024);
        #pragma unroll
        for (int mf = 0; mf < 4; ++mf)
            av0b[mf] = *(const bf16x8*)(Ab + aoff0 + mf * 1024);
        gload_lds16(asrc4,          ad4);
        gload_lds16(asrc4 + 131072, ad4 + 8192);

        asm volatile("s_barrier" ::: "memory");
        asm volatile("s_waitcnt lgkmcnt(0)" ::: "memory");
        __builtin_amdgcn_s_setprio(1);
        #pragma unroll
        for (int mf = 0; mf < 4; ++mf)
            #pragma unroll
            for (int nf = 0; nf < 4; ++nf)
                facc[mf][nf] = __builtin_amdgcn_mfma_f32_16x16x32_bf16(
                    av0b[mf], bvb[nf], facc[mf][nf], 0, 0, 0);
        __builtin_amdgcn_s_setprio(0);
        asm volatile("s_barrier" ::: "memory");

        // ---- ph4: av1_b; stage B(a+4); MFMA hi(b)
        #pragma unroll
        for (int mf = 0; mf < 4; ++mf)
            av1b[mf] = *(const bf16x8*)(Ab + aoff0 + (4 + mf) * 1024);
        gload_lds16(bsrc4,           bd4);
        gload_lds16(bsrc4 + 1048576, bd4 + 8192);

        asm volatile("s_barrier" ::: "memory");
        asm volatile("s_waitcnt lgkmcnt(0)" ::: "memory");
        __builtin_amdgcn_s_setprio(1);
        #pragma unroll
        for (int mf = 0; mf < 4; ++mf)
            #pragma unroll
            for (int nf = 0; nf < 4; ++nf)
                facc[4 + mf][nf] = __builtin_amdgcn_mfma_f32_16x16x32_bf16(
                    av1b[mf], bvb[nf], facc[4 + mf][nf], 0, 0, 0);
        __builtin_amdgcn_s_setprio(0);
        // next pair's top gate (vmcnt+barrier) doubles as ph4's post-barrier
    }

    // drain pending global_load_lds before epilogue / LDS reuse
    asm volatile("s_waitcnt vmcnt(0)" ::: "memory");

    // epilogue: out = GELU(facc * w_7 + bias)
    float bval[4];
    #pragma unroll
    for (int nf = 0; nf < 4; ++nf) bval[nf] = bias[f0 + wn * 64 + nf * 16 + l16];
    #pragma unroll
    for (int mf = 0; mf < 8; ++mf) {
        #pragma unroll
        for (int r = 0; r < 4; ++r) {
            int lrow = wm * 128 + mf * 16 + quad * 4 + r;
            int gm = m0 + lrow;
            float w7 = fmaxf(rws[lrow * 9 + 7], 1e-20f);
            #pragma unroll
            for (int nf = 0; nf < 4; ++nf) {
                float x = facc[mf][nf][r] * w7 + bval[nf];
                float gel = 0.5f * x * (1.0f + erff(x * 0.70710678118f));
                outp[(size_t)gm * DDIM + (f0 + wn * 64 + nf * 16 + l16)] = gel;
            }
        }
    }
}

// ---------------------------------------------------------------------------
extern "C" void kernel_launch(void* const* d_in, const int* in_sizes, int n_in,
                              void* d_out, int out_size, void* d_ws, size_t ws_size,
                              hipStream_t stream) {
    const float* h    = (const float*)d_in[0];   // [4,4096,1024]
    const float* Wr   = (const float*)d_in[1];   // [8,1024]
    const float* br   = (const float*)d_in[2];   // [8]
    const float* We   = (const float*)d_in[3];   // [8,1024,1024]
    const float* bias = (const float*)d_in[4];   // [1024]
    float* outp = (float*)d_out;
    char* ws = (char*)d_ws;

    __bf16* hbf = (__bf16*)ws;                                   // 32 MiB
    __bf16* Bp  = (__bf16*)(ws + (size_t)M_TOK * DDIM * 2);      // 16 MiB
    float*  rwp = (float*)(ws + (size_t)M_TOK * DDIM * 2
                              + (size_t)NEXP * DDIM * DDIM * 2); // 512 KiB

    hipLaunchKernelGGL(prep_kernel, dim3(CONV_BLOCKS + ROUTE_BLOCKS), dim3(256),
                       0, stream, h, Wr, br, We, hbf, rwp, Bp);
    hipLaunchKernelGGL(gemm_fused_kernel, dim3(256), dim3(512),
                       0, stream, hbf, Bp, rwp, bias, outp);
}

// Round 6
// 412.448 us; speedup vs baseline: 1.1365x; 1.1365x over previous
//
#include <hip/hip_runtime.h>
#include <hip/hip_bf16.h>

#define M_TOK 16384   // B*S
#define DDIM  1024
#define NEXP  8
#define KP    (NEXP * DDIM)   // 8192 fused K

typedef __bf16 bf16x8 __attribute__((ext_vector_type(8)));
typedef __bf16 bf16x4 __attribute__((ext_vector_type(4)));
typedef float  floatx4 __attribute__((ext_vector_type(4)));

__device__ __forceinline__ void gload_lds16(const void* g, void* l) {
    __builtin_amdgcn_global_load_lds(
        (__attribute__((address_space(1))) void*)(void*)g,
        (__attribute__((address_space(3))) void*)l,
        16, 0, 0);
}

// ---------------------------------------------------------------------------
// Kernel 1 (merged prep): blocks [0,2048) convert W_edges fp32 -> Bp bf16
// [f][e*1024+k]; blocks [2048,2560) route: 32 rows/block (8/wave), Wr staged
// ONCE per block (was once per 4 rows -> 134 MB redundant L2 traffic).
// ---------------------------------------------------------------------------
#define CONV_BLOCKS  2048
#define ROUTE_BLOCKS 512   // 32 rows per block

__global__ __launch_bounds__(256) void prep_kernel(
    const float* __restrict__ h, const float* __restrict__ Wr,
    const float* __restrict__ br, const float* __restrict__ We,
    __bf16* __restrict__ hbf, float* __restrict__ rw, __bf16* __restrict__ Bp)
{
    __shared__ float Wrs[NEXP * DDIM];
    const int tid = threadIdx.x;

    if (blockIdx.x < CONV_BLOCKS) {
        size_t idx = ((size_t)blockIdx.x * 256 + tid) * 16;
        int e = (int)(idx >> 20);
        int f = (int)(idx >> 10) & 1023;
        int k = (int)idx & 1023;
        const float4* s4 = (const float4*)(We + idx);
        float a[16];
        #pragma unroll
        for (int i = 0; i < 4; ++i) {
            float4 v = s4[i];
            a[i*4+0] = v.x; a[i*4+1] = v.y; a[i*4+2] = v.z; a[i*4+3] = v.w;
        }
        bf16x8 o0, o1;
        #pragma unroll
        for (int i = 0; i < 8; ++i) { o0[i] = (__bf16)a[i]; o1[i] = (__bf16)a[8 + i]; }
        __bf16* d = Bp + (size_t)f * KP + (size_t)e * DDIM + k;
        *(bf16x8*)d       = o0;
        *(bf16x8*)(d + 8) = o1;
        return;
    }

    // ---- route: stage Wr once, then 8 rows per wave
    {
        const float4* s4 = (const float4*)Wr;
        float4* d4 = (float4*)Wrs;
        #pragma unroll
        for (int j = 0; j < 8; ++j) d4[j * 256 + tid] = s4[j * 256 + tid];
    }
    __syncthreads();

    const int wave = tid >> 6, lane = tid & 63;
    const int mbase = (blockIdx.x - CONV_BLOCKS) * 32 + wave * 8;
    const float4* Wrs4 = (const float4*)Wrs;

    #pragma unroll 2
    for (int i = 0; i < 8; ++i) {
        const int m = mbase + i;
        const float4* hrow4 = (const float4*)(h + (size_t)m * DDIM);
        float4 a[4];
        #pragma unroll
        for (int j = 0; j < 4; ++j) a[j] = hrow4[j * 64 + lane];

        #pragma unroll
        for (int j = 0; j < 4; ++j) {
            bf16x4 o;
            o[0] = (__bf16)a[j].x; o[1] = (__bf16)a[j].y;
            o[2] = (__bf16)a[j].z; o[3] = (__bf16)a[j].w;
            *(bf16x4*)(hbf + (size_t)m * DDIM + j * 256 + lane * 4) = o;
        }

        float p[NEXP];
        #pragma unroll
        for (int e = 0; e < NEXP; ++e) {
            float s = 0.f;
            #pragma unroll
            for (int j = 0; j < 4; ++j) {
                float4 wv = Wrs4[e * 256 + j * 64 + lane];
                s += a[j].x*wv.x + a[j].y*wv.y + a[j].z*wv.z + a[j].w*wv.w;
            }
            p[e] = s;
        }
        #pragma unroll
        for (int e = 0; e < NEXP; ++e) {
            #pragma unroll
            for (int off = 32; off > 0; off >>= 1)
                p[e] += __shfl_xor(p[e], off, 64);
        }
        if (lane == 0) {
            float l[NEXP], mx = -1e30f;
            #pragma unroll
            for (int e = 0; e < NEXP; ++e) { l[e] = p[e] + br[e]; mx = fmaxf(mx, l[e]); }
            float s = 0.f;
            #pragma unroll
            for (int e = 0; e < NEXP; ++e) { l[e] = expf(l[e] - mx); s += l[e]; }
            float inv = 1.f / s;
            float4 r0 = {l[0]*inv, l[1]*inv, l[2]*inv, l[3]*inv};
            float4 r1 = {l[4]*inv, l[5]*inv, l[6]*inv, l[7]*inv};
            *(float4*)(rw + (size_t)m * NEXP)     = r0;
            *(float4*)(rw + (size_t)m * NEXP + 4) = r1;
        }
    }
}

// ---------------------------------------------------------------------------
// Kernel 2: fused MoE GEMM — byte-identical to the Round-3 best (285 us,
// MfmaUtil 43%, 0 bank conflicts). 256x256 tile, BK=32, ring-4 LDS, counted
// vmcnt(4), 2-phase-per-tile schedule:
//   [vmcnt(4); bar]  phase1 {ds av0[4]+bv[4], stage A(t+2); bar; lgkm(0);
//                            setprio1; 16 MFMA mf0-3; setprio0}
//                    phase2 {ds av1[4],       stage B(t+2); bar; lgkm(0);
//                            setprio1; 16 MFMA mf4-7; setprio0}
// NO sched_barrier anywhere (m141). Deeper phase splits measured WORSE
// (R5: 4-phase/dual-gate = 350 us / 33%). Do not re-deepen.
//
// Hazards (ring-4, distance-2, staggered stages):
//  - RAW: tile t's 4 loads (A @ t-2.p1, B @ t-2.p2) are the 4 oldest
//    outstanding at t's top gate -> vmcnt(4) + barrier publishes them.
//  - WAR: stage at tile t targets slot u+2; last readers ran at tile t-2,
//    separated by >= 3 barriers. Safe.
//
// Expert rescale invariant: entering expert e, facc = (sum_{i<e} w_i*C_i)/w_e;
// boundary multiplies by w_{e-1}/w_e; epilogue multiplies by w_7.
// rws padded to stride 9 (36B) so quad*4-row strides hit distinct banks.
// ---------------------------------------------------------------------------
__global__ __launch_bounds__(512, 2) void gemm_fused_kernel(
    const __bf16* __restrict__ hbf, const __bf16* __restrict__ Bp,
    const float* __restrict__ rw, const float* __restrict__ bias,
    float* __restrict__ outp)
{
    __shared__ __bf16 As[4][256 * 32];   // 4 x 16 KiB
    __shared__ __bf16 Bs[4][256 * 32];   // 4 x 16 KiB
    __shared__ float  rws[256 * 9];      // 9 KiB, padded stride 9

    const int tid  = threadIdx.x;
    const int wave = tid >> 6, lane = tid & 63;
    const int quad = lane >> 4, l16 = lane & 15;
    const int wm = wave >> 2, wn = wave & 3;          // 2 x 4 wave grid

    // Bijective XCD map: XCD = L&7 (dispatch round-robin). Two XCDs per
    // f-panel -> each XCD's 32 blocks share one 4 MiB B-slice (L2-resident).
    const int L = blockIdx.x;
    const int xcd = L & 7, slotid = L >> 3;
    const int f0 = (xcd >> 1) * 256;
    const int m0 = (((xcd & 1) << 5) + slotid) * 256;

    // stage routing weights for this block's 256 rows into padded LDS
    if (tid < 256) {
        const float4* s = (const float4*)(rw + ((size_t)m0 + tid) * NEXP);
        float4 x0 = s[0], x1 = s[1];
        float* d = &rws[tid * 9];
        d[0] = x0.x; d[1] = x0.y; d[2] = x0.z; d[3] = x0.w;
        d[4] = x1.x; d[5] = x1.y; d[6] = x1.z; d[7] = x1.w;
    }

    // LDS read offsets: row = 64B (4 groups of 16B); group swizzle g^=(row>>1)&3.
    const int arow = wm * 128 + l16;
    const int brow = wn * 64  + l16;
    const int aoff0 = (arow * 4 + (quad ^ ((arow >> 1) & 3))) * 16;
    const int boff0 = (brow * 4 + (quad ^ ((brow >> 1) & 3))) * 16;

    // staging: chunk c dst byte = c*8192 + tid*16; row = c*128 + (tid>>2);
    // pre-swizzled global source group (row+128 preserves (row>>1)&3)
    const int srow = tid >> 2;
    const int scol = ((tid & 3) ^ ((srow >> 1) & 3)) * 8;
    const size_t aBase = (size_t)(m0 + srow) * DDIM + scol;
    const size_t bBase = (size_t)(f0 + srow) * KP + scol;

    floatx4 facc[8][4];
    const floatx4 z4 = {0.f, 0.f, 0.f, 0.f};
    #pragma unroll
    for (int i = 0; i < 8; ++i)
        #pragma unroll
        for (int j = 0; j < 4; ++j) facc[i][j] = z4;

    __syncthreads();   // rws visible

    // prologue: stage tiles 0 (oldest 4 loads) and 1
    {
        const __bf16* a0 = hbf + aBase;
        const __bf16* b0 = Bp  + bBase;
        gload_lds16(a0,                 (char*)&As[0][0] + tid * 16);
        gload_lds16(b0,                 (char*)&Bs[0][0] + tid * 16);
        gload_lds16(a0 + 131072,        (char*)&As[0][0] + tid * 16 + 8192);
        gload_lds16(b0 + 1048576,       (char*)&Bs[0][0] + tid * 16 + 8192);
        gload_lds16(a0 + 32,            (char*)&As[1][0] + tid * 16);
        gload_lds16(b0 + 32,            (char*)&Bs[1][0] + tid * 16);
        gload_lds16(a0 + 131072 + 32,   (char*)&As[1][0] + tid * 16 + 8192);
        gload_lds16(b0 + 1048576 + 32,  (char*)&Bs[1][0] + tid * 16 + 8192);
    }

    #pragma unroll 1
    for (int tb = 0; tb < 64; ++tb) {
        if (tb && (tb & 7) == 0) {
            const int e = tb >> 3;   // entering expert e
            #pragma unroll
            for (int mf = 0; mf < 8; ++mf) {
                #pragma unroll
                for (int r = 0; r < 4; ++r) {
                    int row = wm * 128 + mf * 16 + quad * 4 + r;
                    float wp = fmaxf(rws[row * 9 + e - 1], 1e-20f);
                    float wc = fmaxf(rws[row * 9 + e],     1e-20f);
                    float ratio = wp / wc;
                    #pragma unroll
                    for (int nf = 0; nf < 4; ++nf) facc[mf][nf][r] *= ratio;
                }
            }
        }
        #pragma unroll
        for (int u = 0; u < 4; ++u) {
            const int t  = (tb << 2) + u;
            const int tt = (t + 2) & 255;               // staged tile (wrap: harmless)
            const __bf16* asrc = hbf + aBase + (size_t)((tt & 31) << 5);
            const __bf16* bsrc = Bp  + bBase + ((size_t)tt << 5);
            char* ad = (char*)&As[(u + 2) & 3][0] + tid * 16;
            char* bd = (char*)&Bs[(u + 2) & 3][0] + tid * 16;
            const char* Ab = (const char*)&As[u][0];
            const char* Bb = (const char*)&Bs[u][0];

            asm volatile("s_waitcnt vmcnt(4)" ::: "memory");
            asm volatile("s_barrier" ::: "memory");

            // ---- phase 1: fragments for mf0-3 + B; stage next A-tile
            bf16x8 av0[4], av1[4], bv[4];
            #pragma unroll
            for (int nf = 0; nf < 4; ++nf)
                bv[nf] = *(const bf16x8*)(Bb + boff0 + nf * 1024);
            #pragma unroll
            for (int mf = 0; mf < 4; ++mf)
                av0[mf] = *(const bf16x8*)(Ab + aoff0 + mf * 1024);
            gload_lds16(asrc,          ad);
            gload_lds16(asrc + 131072, ad + 8192);

            asm volatile("s_barrier" ::: "memory");
            asm volatile("s_waitcnt lgkmcnt(0)" ::: "memory");
            __builtin_amdgcn_s_setprio(1);
            #pragma unroll
            for (int mf = 0; mf < 4; ++mf)
                #pragma unroll
                for (int nf = 0; nf < 4; ++nf)
                    facc[mf][nf] = __builtin_amdgcn_mfma_f32_16x16x32_bf16(
                        av0[mf], bv[nf], facc[mf][nf], 0, 0, 0);
            __builtin_amdgcn_s_setprio(0);

            // ---- phase 2: fragments for mf4-7; stage next B-tile
            #pragma unroll
            for (int mf = 0; mf < 4; ++mf)
                av1[mf] = *(const bf16x8*)(Ab + aoff0 + (4 + mf) * 1024);
            gload_lds16(bsrc,           bd);
            gload_lds16(bsrc + 1048576, bd + 8192);

            asm volatile("s_barrier" ::: "memory");
            asm volatile("s_waitcnt lgkmcnt(0)" ::: "memory");
            __builtin_amdgcn_s_setprio(1);
            #pragma unroll
            for (int mf = 0; mf < 4; ++mf)
                #pragma unroll
                for (int nf = 0; nf < 4; ++nf)
                    facc[4 + mf][nf] = __builtin_amdgcn_mfma_f32_16x16x32_bf16(
                        av1[mf], bv[nf], facc[4 + mf][nf], 0, 0, 0);
            __builtin_amdgcn_s_setprio(0);
        }
    }

    // drain pending global_load_lds before epilogue / LDS reuse
    asm volatile("s_waitcnt vmcnt(0)" ::: "memory");

    // epilogue: out = GELU(facc * w_7 + bias)
    float bval[4];
    #pragma unroll
    for (int nf = 0; nf < 4; ++nf) bval[nf] = bias[f0 + wn * 64 + nf * 16 + l16];
    #pragma unroll
    for (int mf = 0; mf < 8; ++mf) {
        #pragma unroll
        for (int r = 0; r < 4; ++r) {
            int lrow = wm * 128 + mf * 16 + quad * 4 + r;
            int gm = m0 + lrow;
            float w7 = fmaxf(rws[lrow * 9 + 7], 1e-20f);
            #pragma unroll
            for (int nf = 0; nf < 4; ++nf) {
                float x = facc[mf][nf][r] * w7 + bval[nf];
                float gel = 0.5f * x * (1.0f + erff(x * 0.70710678118f));
                outp[(size_t)gm * DDIM + (f0 + wn * 64 + nf * 16 + l16)] = gel;
            }
        }
    }
}

// ---------------------------------------------------------------------------
extern "C" void kernel_launch(void* const* d_in, const int* in_sizes, int n_in,
                              void* d_out, int out_size, void* d_ws, size_t ws_size,
                              hipStream_t stream) {
    const float* h    = (const float*)d_in[0];   // [4,4096,1024]
    const float* Wr   = (const float*)d_in[1];   // [8,1024]
    const float* br   = (const float*)d_in[2];   // [8]
    const float* We   = (const float*)d_in[3];   // [8,1024,1024]
    const float* bias = (const float*)d_in[4];   // [1024]
    float* outp = (float*)d_out;
    char* ws = (char*)d_ws;

    __bf16* hbf = (__bf16*)ws;                                   // 32 MiB
    __bf16* Bp  = (__bf16*)(ws + (size_t)M_TOK * DDIM * 2);      // 16 MiB
    float*  rwp = (float*)(ws + (size_t)M_TOK * DDIM * 2
                              + (size_t)NEXP * DDIM * DDIM * 2); // 512 KiB

    hipLaunchKernelGGL(prep_kernel, dim3(CONV_BLOCKS + ROUTE_BLOCKS), dim3(256),
                       0, stream, h, Wr, br, We, hbf, rwp, Bp);
    hipLaunchKernelGGL(gemm_fused_kernel, dim3(256), dim3(512),
                       0, stream, hbf, Bp, rwp, bias, outp);
}

// Round 8
// 406.156 us; speedup vs baseline: 1.1541x; 1.0155x over previous
//
#include <hip/hip_runtime.h>
#include <hip/hip_bf16.h>

#define M_TOK 16384   // B*S
#define DDIM  1024
#define NEXP  8
#define KP    (NEXP * DDIM)   // 8192 fused K

typedef __bf16 bf16x8 __attribute__((ext_vector_type(8)));
typedef __bf16 bf16x4 __attribute__((ext_vector_type(4)));
typedef float  floatx4 __attribute__((ext_vector_type(4)));

__device__ __forceinline__ void gload_lds16(const void* g, void* l) {
    __builtin_amdgcn_global_load_lds(
        (__attribute__((address_space(1))) void*)(void*)g,
        (__attribute__((address_space(3))) void*)l,
        16, 0, 0);
}

// ---------------------------------------------------------------------------
// Kernel 1 (merged prep): blocks [0,2048) convert W_edges fp32 -> Bp bf16
// [f][e*1024+k]; blocks [2048,2560) route: 32 rows/block (8/wave), Wr staged
// once per block. NOTE (R6 finding): prep internals are NOT on the critical
// path — total was identical across 3 prep designs; residual non-gemm time
// is fixed harness/graph cost. Do not churn this kernel further.
// ---------------------------------------------------------------------------
#define CONV_BLOCKS  2048
#define ROUTE_BLOCKS 512   // 32 rows per block

__global__ __launch_bounds__(256) void prep_kernel(
    const float* __restrict__ h, const float* __restrict__ Wr,
    const float* __restrict__ br, const float* __restrict__ We,
    __bf16* __restrict__ hbf, float* __restrict__ rw, __bf16* __restrict__ Bp)
{
    __shared__ float Wrs[NEXP * DDIM];
    const int tid = threadIdx.x;

    if (blockIdx.x < CONV_BLOCKS) {
        size_t idx = ((size_t)blockIdx.x * 256 + tid) * 16;
        int e = (int)(idx >> 20);
        int f = (int)(idx >> 10) & 1023;
        int k = (int)idx & 1023;
        const float4* s4 = (const float4*)(We + idx);
        float a[16];
        #pragma unroll
        for (int i = 0; i < 4; ++i) {
            float4 v = s4[i];
            a[i*4+0] = v.x; a[i*4+1] = v.y; a[i*4+2] = v.z; a[i*4+3] = v.w;
        }
        bf16x8 o0, o1;
        #pragma unroll
        for (int i = 0; i < 8; ++i) { o0[i] = (__bf16)a[i]; o1[i] = (__bf16)a[8 + i]; }
        __bf16* d = Bp + (size_t)f * KP + (size_t)e * DDIM + k;
        *(bf16x8*)d       = o0;
        *(bf16x8*)(d + 8) = o1;
        return;
    }

    // ---- route: stage Wr once, then 8 rows per wave
    {
        const float4* s4 = (const float4*)Wr;
        float4* d4 = (float4*)Wrs;
        #pragma unroll
        for (int j = 0; j < 8; ++j) d4[j * 256 + tid] = s4[j * 256 + tid];
    }
    __syncthreads();

    const int wave = tid >> 6, lane = tid & 63;
    const int mbase = (blockIdx.x - CONV_BLOCKS) * 32 + wave * 8;
    const float4* Wrs4 = (const float4*)Wrs;

    #pragma unroll 2
    for (int i = 0; i < 8; ++i) {
        const int m = mbase + i;
        const float4* hrow4 = (const float4*)(h + (size_t)m * DDIM);
        float4 a[4];
        #pragma unroll
        for (int j = 0; j < 4; ++j) a[j] = hrow4[j * 64 + lane];

        #pragma unroll
        for (int j = 0; j < 4; ++j) {
            bf16x4 o;
            o[0] = (__bf16)a[j].x; o[1] = (__bf16)a[j].y;
            o[2] = (__bf16)a[j].z; o[3] = (__bf16)a[j].w;
            *(bf16x4*)(hbf + (size_t)m * DDIM + j * 256 + lane * 4) = o;
        }

        float p[NEXP];
        #pragma unroll
        for (int e = 0; e < NEXP; ++e) {
            float s = 0.f;
            #pragma unroll
            for (int j = 0; j < 4; ++j) {
                float4 wv = Wrs4[e * 256 + j * 64 + lane];
                s += a[j].x*wv.x + a[j].y*wv.y + a[j].z*wv.z + a[j].w*wv.w;
            }
            p[e] = s;
        }
        #pragma unroll
        for (int e = 0; e < NEXP; ++e) {
            #pragma unroll
            for (int off = 32; off > 0; off >>= 1)
                p[e] += __shfl_xor(p[e], off, 64);
        }
        if (lane == 0) {
            float l[NEXP], mx = -1e30f;
            #pragma unroll
            for (int e = 0; e < NEXP; ++e) { l[e] = p[e] + br[e]; mx = fmaxf(mx, l[e]); }
            float s = 0.f;
            #pragma unroll
            for (int e = 0; e < NEXP; ++e) { l[e] = expf(l[e] - mx); s += l[e]; }
            float inv = 1.f / s;
            float4 r0 = {l[0]*inv, l[1]*inv, l[2]*inv, l[3]*inv};
            float4 r1 = {l[4]*inv, l[5]*inv, l[6]*inv, l[7]*inv};
            *(float4*)(rw + (size_t)m * NEXP)     = r0;
            *(float4*)(rw + (size_t)m * NEXP + 4) = r1;
        }
    }
}

// ---------------------------------------------------------------------------
// Kernel 2: fused MoE GEMM. R3 structure (285 us / MfmaUtil 43%) with the
// two hard `s_waitcnt lgkmcnt(0)` pins REMOVED (this round's single change):
// C++ ds_reads let the compiler emit counted lgkmcnt(N) waits, so the first
// MFMAs issue while later fragment reads are still in flight — overlapping
// the ~380-cyc read drain with the matrix pipe. Pins are only required for
// inline-asm ds_reads (rule #18), which these are not.
//
// Schedule per K-32 tile (ring-4 LDS, distance-2 staging, vmcnt(4) gate):
//   [vmcnt(4); bar]  phase1 {ds av0[4]+bv[4], stage A(t+2); bar;
//                            setprio1; 16 MFMA mf0-3; setprio0}
//                    phase2 {ds av1[4],       stage B(t+2); bar;
//                            setprio1; 16 MFMA mf4-7; setprio0}
// NO sched_barrier (m141). Deeper phase splits measured WORSE (R5: 350 us).
//
// Hazards: RAW — tile t's 4 loads are the 4 oldest outstanding at t's gate
// -> vmcnt(4)+barrier publishes them before any read of slot u. WAR — stage
// at tile t targets slot u+2, last read at tile t-2, >= 3 barriers earlier.
// Reads cannot be hoisted above the asm barriers ("memory" clobber); MFMA
// ordering is pure register dataflow, so removing the pins is corr-neutral.
//
// Expert rescale invariant: entering expert e, facc = (sum_{i<e} w_i*C_i)/w_e;
// boundary multiplies by w_{e-1}/w_e; epilogue multiplies by w_7.
// rws padded to stride 9 (36B) so quad*4-row strides hit distinct banks.
// ---------------------------------------------------------------------------
__global__ __launch_bounds__(512, 2) void gemm_fused_kernel(
    const __bf16* __restrict__ hbf, const __bf16* __restrict__ Bp,
    const float* __restrict__ rw, const float* __restrict__ bias,
    float* __restrict__ outp)
{
    __shared__ __bf16 As[4][256 * 32];   // 4 x 16 KiB
    __shared__ __bf16 Bs[4][256 * 32];   // 4 x 16 KiB
    __shared__ float  rws[256 * 9];      // 9 KiB, padded stride 9

    const int tid  = threadIdx.x;
    const int wave = tid >> 6, lane = tid & 63;
    const int quad = lane >> 4, l16 = lane & 15;
    const int wm = wave >> 2, wn = wave & 3;          // 2 x 4 wave grid

    // Bijective XCD map: XCD = L&7 (dispatch round-robin). Two XCDs per
    // f-panel -> each XCD's 32 blocks share one 4 MiB B-slice (L2-resident).
    const int L = blockIdx.x;
    const int xcd = L & 7, slotid = L >> 3;
    const int f0 = (xcd >> 1) * 256;
    const int m0 = (((xcd & 1) << 5) + slotid) * 256;

    // stage routing weights for this block's 256 rows into padded LDS
    if (tid < 256) {
        const float4* s = (const float4*)(rw + ((size_t)m0 + tid) * NEXP);
        float4 x0 = s[0], x1 = s[1];
        float* d = &rws[tid * 9];
        d[0] = x0.x; d[1] = x0.y; d[2] = x0.z; d[3] = x0.w;
        d[4] = x1.x; d[5] = x1.y; d[6] = x1.z; d[7] = x1.w;
    }

    // LDS read offsets: row = 64B (4 groups of 16B); group swizzle g^=(row>>1)&3.
    const int arow = wm * 128 + l16;
    const int brow = wn * 64  + l16;
    const int aoff0 = (arow * 4 + (quad ^ ((arow >> 1) & 3))) * 16;
    const int boff0 = (brow * 4 + (quad ^ ((brow >> 1) & 3))) * 16;

    // staging: chunk c dst byte = c*8192 + tid*16; row = c*128 + (tid>>2);
    // pre-swizzled global source group (row+128 preserves (row>>1)&3)
    const int srow = tid >> 2;
    const int scol = ((tid & 3) ^ ((srow >> 1) & 3)) * 8;
    const size_t aBase = (size_t)(m0 + srow) * DDIM + scol;
    const size_t bBase = (size_t)(f0 + srow) * KP + scol;

    floatx4 facc[8][4];
    const floatx4 z4 = {0.f, 0.f, 0.f, 0.f};
    #pragma unroll
    for (int i = 0; i < 8; ++i)
        #pragma unroll
        for (int j = 0; j < 4; ++j) facc[i][j] = z4;

    __syncthreads();   // rws visible

    // prologue: stage tiles 0 (oldest 4 loads) and 1
    {
        const __bf16* a0 = hbf + aBase;
        const __bf16* b0 = Bp  + bBase;
        gload_lds16(a0,                 (char*)&As[0][0] + tid * 16);
        gload_lds16(b0,                 (char*)&Bs[0][0] + tid * 16);
        gload_lds16(a0 + 131072,        (char*)&As[0][0] + tid * 16 + 8192);
        gload_lds16(b0 + 1048576,       (char*)&Bs[0][0] + tid * 16 + 8192);
        gload_lds16(a0 + 32,            (char*)&As[1][0] + tid * 16);
        gload_lds16(b0 + 32,            (char*)&Bs[1][0] + tid * 16);
        gload_lds16(a0 + 131072 + 32,   (char*)&As[1][0] + tid * 16 + 8192);
        gload_lds16(b0 + 1048576 + 32,  (char*)&Bs[1][0] + tid * 16 + 8192);
    }

    #pragma unroll 1
    for (int tb = 0; tb < 64; ++tb) {
        if (tb && (tb & 7) == 0) {
            const int e = tb >> 3;   // entering expert e
            #pragma unroll
            for (int mf = 0; mf < 8; ++mf) {
                #pragma unroll
                for (int r = 0; r < 4; ++r) {
                    int row = wm * 128 + mf * 16 + quad * 4 + r;
                    float wp = fmaxf(rws[row * 9 + e - 1], 1e-20f);
                    float wc = fmaxf(rws[row * 9 + e],     1e-20f);
                    float ratio = wp / wc;
                    #pragma unroll
                    for (int nf = 0; nf < 4; ++nf) facc[mf][nf][r] *= ratio;
                }
            }
        }
        #pragma unroll
        for (int u = 0; u < 4; ++u) {
            const int t  = (tb << 2) + u;
            const int tt = (t + 2) & 255;               // staged tile (wrap: harmless)
            const __bf16* asrc = hbf + aBase + (size_t)((tt & 31) << 5);
            const __bf16* bsrc = Bp  + bBase + ((size_t)tt << 5);
            char* ad = (char*)&As[(u + 2) & 3][0] + tid * 16;
            char* bd = (char*)&Bs[(u + 2) & 3][0] + tid * 16;
            const char* Ab = (const char*)&As[u][0];
            const char* Bb = (const char*)&Bs[u][0];

            asm volatile("s_waitcnt vmcnt(4)" ::: "memory");
            asm volatile("s_barrier" ::: "memory");

            // ---- phase 1: fragments for mf0-3 + B; stage next A-tile
            bf16x8 av0[4], av1[4], bv[4];
            #pragma unroll
            for (int nf = 0; nf < 4; ++nf)
                bv[nf] = *(const bf16x8*)(Bb + boff0 + nf * 1024);
            #pragma unroll
            for (int mf = 0; mf < 4; ++mf)
                av0[mf] = *(const bf16x8*)(Ab + aoff0 + mf * 1024);
            gload_lds16(asrc,          ad);
            gload_lds16(asrc + 131072, ad + 8192);

            asm volatile("s_barrier" ::: "memory");
            // no lgkmcnt(0) pin: compiler emits counted waits, first MFMAs
            // overlap the remaining fragment reads
            __builtin_amdgcn_s_setprio(1);
            #pragma unroll
            for (int mf = 0; mf < 4; ++mf)
                #pragma unroll
                for (int nf = 0; nf < 4; ++nf)
                    facc[mf][nf] = __builtin_amdgcn_mfma_f32_16x16x32_bf16(
                        av0[mf], bv[nf], facc[mf][nf], 0, 0, 0);
            __builtin_amdgcn_s_setprio(0);

            // ---- phase 2: fragments for mf4-7; stage next B-tile
            #pragma unroll
            for (int mf = 0; mf < 4; ++mf)
                av1[mf] = *(const bf16x8*)(Ab + aoff0 + (4 + mf) * 1024);
            gload_lds16(bsrc,           bd);
            gload_lds16(bsrc + 1048576, bd + 8192);

            asm volatile("s_barrier" ::: "memory");
            // no lgkmcnt(0) pin here either
            __builtin_amdgcn_s_setprio(1);
            #pragma unroll
            for (int mf = 0; mf < 4; ++mf)
                #pragma unroll
                for (int nf = 0; nf < 4; ++nf)
                    facc[4 + mf][nf] = __builtin_amdgcn_mfma_f32_16x16x32_bf16(
                        av1[mf], bv[nf], facc[4 + mf][nf], 0, 0, 0);
            __builtin_amdgcn_s_setprio(0);
        }
    }

    // drain pending global_load_lds before epilogue / LDS reuse
    asm volatile("s_waitcnt vmcnt(0)" ::: "memory");

    // epilogue: out = GELU(facc * w_7 + bias)
    float bval[4];
    #pragma unroll
    for (int nf = 0; nf < 4; ++nf) bval[nf] = bias[f0 + wn * 64 + nf * 16 + l16];
    #pragma unroll
    for (int mf = 0; mf < 8; ++mf) {
        #pragma unroll
        for (int r = 0; r < 4; ++r) {
            int lrow = wm * 128 + mf * 16 + quad * 4 + r;
            int gm = m0 + lrow;
            float w7 = fmaxf(rws[lrow * 9 + 7], 1e-20f);
            #pragma unroll
            for (int nf = 0; nf < 4; ++nf) {
                float x = facc[mf][nf][r] * w7 + bval[nf];
                float gel = 0.5f * x * (1.0f + erff(x * 0.70710678118f));
                outp[(size_t)gm * DDIM + (f0 + wn * 64 + nf * 16 + l16)] = gel;
            }
        }
    }
}

// ---------------------------------------------------------------------------
extern "C" void kernel_launch(void* const* d_in, const int* in_sizes, int n_in,
                              void* d_out, int out_size, void* d_ws, size_t ws_size,
                              hipStream_t stream) {
    const float* h    = (const float*)d_in[0];   // [4,4096,1024]
    const float* Wr   = (const float*)d_in[1];   // [8,1024]
    const float* br   = (const float*)d_in[2];   // [8]
    const float* We   = (const float*)d_in[3];   // [8,1024,1024]
    const float* bias = (const float*)d_in[4];   // [1024]
    float* outp = (float*)d_out;
    char* ws = (char*)d_ws;

    __bf16* hbf = (__bf16*)ws;                                   // 32 MiB
    __bf16* Bp  = (__bf16*)(ws + (size_t)M_TOK * DDIM * 2);      // 16 MiB
    float*  rwp = (float*)(ws + (size_t)M_TOK * DDIM * 2
                              + (size_t)NEXP * DDIM * DDIM * 2); // 512 KiB

    hipLaunchKernelGGL(prep_kernel, dim3(CONV_BLOCKS + ROUTE_BLOCKS), dim3(256),
                       0, stream, h, Wr, br, We, hbf, rwp, Bp);
    hipLaunchKernelGGL(gemm_fused_kernel, dim3(256), dim3(512),
                       0, stream, hbf, Bp, rwp, bias, outp);
}